// Round 12
// baseline (69.777 us; speedup 1.0000x reference)
//
#include <hip/hip_runtime.h>
#include <hip/hip_bf16.h>
#include <stdint.h>

typedef __attribute__((ext_vector_type(4))) int          i32x4;
typedef __attribute__((ext_vector_type(8))) int          i32x8;
typedef __attribute__((ext_vector_type(4))) float        f32x4;
typedef __attribute__((ext_vector_type(4))) unsigned int u32x4;

#define MDIM   4096
#define NDIM   4096
#define KBYTES 2048   // K=4096 fp4 elems -> 2048 packed bytes per row
#define NKBLK  128    // K/32 scale blocks per row

#define BM   128
#define BN   128
#define BKB  128                 // K-bytes per step (= 256 fp4 elems = 8 scale blocks)
#define KT   (KBYTES / BKB)      // 16 K-steps

#define BARF()  asm volatile("s_barrier" ::: "memory")
#define LGKM0() asm volatile("s_waitcnt lgkmcnt(0)" ::: "memory")
#define VM0()   asm volatile("s_waitcnt vmcnt(0)" ::: "memory")

// ---------------- repack bytes: int32-per-byte -> packed bytes (u32x4) ----------
// grid = 524288 threads: one u32x4 (16 packed bytes) per matrix per thread.
__global__ void repack_bytes(const int* __restrict__ a, const int* __restrict__ b,
                             u32x4* __restrict__ ap, u32x4* __restrict__ bp) {
  const size_t i = (size_t)(blockIdx.x * blockDim.x + threadIdx.x);
  uint32_t r[4], s[4];
#pragma unroll
  for (int q = 0; q < 4; ++q) {
    i32x4 va = *(const i32x4*)(a + i * 16 + q * 4);
    r[q] = (uint32_t)(va.x & 255) | ((uint32_t)(va.y & 255) << 8) |
           ((uint32_t)(va.z & 255) << 16) | ((uint32_t)(va.w & 255) << 24);
    i32x4 vb = *(const i32x4*)(b + i * 16 + q * 4);
    s[q] = (uint32_t)(vb.x & 255) | ((uint32_t)(vb.y & 255) << 8) |
           ((uint32_t)(vb.z & 255) << 16) | ((uint32_t)(vb.w & 255) << 24);
  }
  u32x4 rv = {r[0], r[1], r[2], r[3]};
  u32x4 sv = {s[0], s[1], s[2], s[3]};
  ap[i] = rv;
  bp[i] = sv;
}

// ---- scale repack with LDS transpose: coalesced reads AND writes --------------
// Target layout (R10/R11-proven): [kt(16)][rowblk(32)][kb&7(8)][m&15(16)][(m>>4)&7(8)]
// One (kt,rowblk) block = 1 KB. Grid: 512 blocks (kt = b&15, rowblk = b>>4),
// 256 threads; per block handles A and B.
__global__ void repack_scales(const float* __restrict__ sa, const float* __restrict__ sb,
                              uint8_t* __restrict__ satT, uint8_t* __restrict__ sbtT) {
  __shared__ uint8_t ls[2][1024];
  const int kt = blockIdx.x & 15, rb = blockIdx.x >> 4;
  const int t  = threadIdx.x;
  const int mm = t >> 1;                 // row within rowblk, 0..127
  const int j0 = (t & 1) * 4;            // kb sub-offset 0 or 4
  const size_t src = (size_t)(rb * 128 + mm) * 128 + kt * 8 + j0;
  const f32x4 va = *(const f32x4*)(sa + src);
  const f32x4 vb = *(const f32x4*)(sb + src);
#pragma unroll
  for (int q = 0; q < 4; ++q) {
    const int o = (j0 + q) * 128 + (mm & 15) * 8 + ((mm >> 4) & 7);
    ls[0][o] = (uint8_t)(int)va[q];
    ls[1][o] = (uint8_t)(int)vb[q];
  }
  __syncthreads();
  const size_t dst = ((size_t)kt * 32 + rb) * 1024 + t * 4;
  *(uint32_t*)(satT + dst) = *(const uint32_t*)&ls[0][t * 4];
  *(uint32_t*)(sbtT + dst) = *(const uint32_t*)&ls[1][t * 4];
}

__device__ __forceinline__ i32x8 frag8(i32x4 v) {
  i32x8 r = {v.x, v.y, v.z, v.w, 0, 0, 0, 0};
  return r;
}

// ---- MXFP4 GEMM: R11 structure + HW opsel byte-select for scales --------------
// 128x128 tile, BK=128B, single buffer, 2 barriers/step, 32 MFMA/step/wave,
// 4 blocks/CU. LDS: A 16K + B 16K + scales 2K = 34816 B.
__global__ __launch_bounds__(256, 4) void mxfp4_gemm(
    const uint8_t* __restrict__ ap, const uint8_t* __restrict__ bp,
    const uint8_t* __restrict__ satT, const uint8_t* __restrict__ sbtT,
    float* __restrict__ out) {
  __shared__ __align__(16) uint8_t lds[34816];

  const int tid  = threadIdx.x;
  const int lane = tid & 63;
  const int w    = tid >> 6;        // wave 0..3
  const int wrow = w >> 1;          // 2x2 wave grid, 64x64 out each
  const int wcol = w & 1;
  const int g    = lane >> 4;       // k-group 0..3 (one scale block each)
  const int l15  = lane & 15;
  const int lx   = lane & 7;        // read-side xor (== frag row & 7)

  // XCD-aware bijective swizzle (nwg=1024, %8==0)
  const int wgid = (blockIdx.x & 7) * 128 + (blockIdx.x >> 3);
  const int bx = wgid & 31;
  const int by = wgid >> 5;

  const uint8_t* aBase = ap + (size_t)(by * BM) * KBYTES;
  const uint8_t* bBase = bp + (size_t)(bx * BN) * KBYTES;
  uint8_t* const lA  = lds;
  uint8_t* const lB  = lds + 16384;
  uint8_t* const scb = lds + 32768;

  // R1-proven zero-conflict swizzle: LDS[row][d] holds global slot d^(row&7)
  const int srow  = lane >> 3;
  const int sslot = (lane & 7) ^ srow;
  const int soff  = srow * KBYTES + sslot * 16;
  const int arow0 = w * 32;

#define STAGE(ktX)                                                                        \
  do {                                                                                    \
    _Pragma("unroll")                                                                     \
    for (int c = 0; c < 4; ++c) {                                                         \
      const int r0 = arow0 + c * 8;                                                       \
      __builtin_amdgcn_global_load_lds(                                                   \
          (__attribute__((address_space(1))) void*)(aBase + (size_t)r0 * KBYTES + (ktX) * BKB + soff), \
          (__attribute__((address_space(3))) void*)(lA + r0 * 128), 16, 0, 0);            \
      __builtin_amdgcn_global_load_lds(                                                   \
          (__attribute__((address_space(1))) void*)(bBase + (size_t)r0 * KBYTES + (ktX) * BKB + soff), \
          (__attribute__((address_space(3))) void*)(lB + r0 * 128), 16, 0, 0);            \
    }                                                                                     \
    __builtin_amdgcn_global_load_lds(                                                     \
        (__attribute__((address_space(1))) void*)(satT + ((size_t)(ktX) * 32 + by) * 1024 + lane * 16), \
        (__attribute__((address_space(3))) void*)(scb + lane * 16), 16, 0, 0);            \
    __builtin_amdgcn_global_load_lds(                                                     \
        (__attribute__((address_space(1))) void*)(sbtT + ((size_t)(ktX) * 32 + bx) * 1024 + lane * 16), \
        (__attribute__((address_space(3))) void*)(scb + 1024 + lane * 16), 16, 0, 0);     \
  } while (0)

// HW byte-select: opsel_a = ms literal picks byte ms of the packed A-scale
// dword; opsel_b = ns picks byte ns of the B-scale dword. No VALU extraction.
#define MM(msL, nsL, sAv, sBv)                                                            \
  acc[msL][nsL] = __builtin_amdgcn_mfma_scale_f32_16x16x128_f8f6f4(                       \
      frag8(af[msL]), frag8(bf[nsL]), acc[msL][nsL], 4, 4, msL, (int)(sAv), nsL, (int)(sBv))
#define MMROW(msL, sAv, sBv)                                                              \
  MM(msL, 0, sAv, sBv); MM(msL, 1, sAv, sBv); MM(msL, 2, sAv, sBv); MM(msL, 3, sAv, sBv)

  f32x4 acc[4][4] = {};
  i32x4 af[4], bf[4];

  STAGE(0);

  for (int kt = 0; kt < KT; ++kt) {
    VM0();     // own 10 staging ops landed; barrier => all waves' landed
    BARF();

    const uint32_t sAk0 = *(const uint32_t*)(scb + (0 + g) * 128 + l15 * 8 + wrow * 4);
    const uint32_t sAk1 = *(const uint32_t*)(scb + (4 + g) * 128 + l15 * 8 + wrow * 4);
    const uint32_t sBk0 = *(const uint32_t*)(scb + 1024 + (0 + g) * 128 + l15 * 8 + wcol * 4);
    const uint32_t sBk1 = *(const uint32_t*)(scb + 1024 + (4 + g) * 128 + l15 * 8 + wcol * 4);

    // ---- kw0: K elems 0..127 ----
    {
      const int slotx = ((0 + g) ^ lx) * 16;
#pragma unroll
      for (int ns = 0; ns < 4; ++ns)
        bf[ns] = *(const i32x4*)(lB + (wcol * 64 + ns * 16 + l15) * 128 + slotx);
#pragma unroll
      for (int ms = 0; ms < 4; ++ms)
        af[ms] = *(const i32x4*)(lA + (wrow * 64 + ms * 16 + l15) * 128 + slotx);
      __builtin_amdgcn_s_setprio(1);
      MMROW(0, sAk0, sBk0);
      MMROW(1, sAk0, sBk0);
      MMROW(2, sAk0, sBk0);
      MMROW(3, sAk0, sBk0);
      __builtin_amdgcn_s_setprio(0);
    }
    // ---- kw1: K elems 128..255 ----
    {
      const int slotx = ((4 + g) ^ lx) * 16;
#pragma unroll
      for (int ns = 0; ns < 4; ++ns)
        bf[ns] = *(const i32x4*)(lB + (wcol * 64 + ns * 16 + l15) * 128 + slotx);
#pragma unroll
      for (int ms = 0; ms < 4; ++ms)
        af[ms] = *(const i32x4*)(lA + (wrow * 64 + ms * 16 + l15) * 128 + slotx);
      __builtin_amdgcn_s_setprio(1);
      MMROW(0, sAk1, sBk1);
      MMROW(1, sAk1, sBk1);
      MMROW(2, sAk1, sBk1);
      MMROW(3, sAk1, sBk1);
      __builtin_amdgcn_s_setprio(0);
    }

    LGKM0();   // all reads complete -> buffer free
    BARF();
    if (kt + 1 < KT) STAGE(kt + 1);
  }

  // epilogue: D mapping row=(lane>>4)*4+r, col=lane&15 per 16x16 block
  float* ob = out + (size_t)(by * BM + wrow * 64) * NDIM + bx * BN + wcol * 64;
#pragma unroll
  for (int ms = 0; ms < 4; ++ms)
#pragma unroll
    for (int ns = 0; ns < 4; ++ns) {
#pragma unroll
      for (int r = 0; r < 4; ++r)
        ob[(size_t)(ms * 16 + g * 4 + r) * NDIM + ns * 16 + l15] = acc[ms][ns][r];
    }
#undef STAGE
#undef MM
#undef MMROW
}

extern "C" void kernel_launch(void* const* d_in, const int* in_sizes, int n_in,
                              void* d_out, int out_size, void* d_ws, size_t ws_size,
                              hipStream_t stream) {
  (void)in_sizes; (void)n_in; (void)out_size; (void)ws_size;
  const int*   a  = (const int*)d_in[0];
  const int*   b  = (const int*)d_in[1];
  const float* sa = (const float*)d_in[2];
  const float* sb = (const float*)d_in[3];
  float* out = (float*)d_out;

  uint8_t* ws = (uint8_t*)d_ws;
  u32x4*   ap   = (u32x4*)ws;                            // 8 MB packed A
  u32x4*   bp   = (u32x4*)(ws + (8u << 20));             // 8 MB packed B
  uint8_t* satT = ws + (16u << 20);                      // 512 KB scales A (tiled)
  uint8_t* sbtT = ws + (16u << 20) + (512u << 10);       // 512 KB scales B (tiled)

  repack_bytes<<<2048, 256, 0, stream>>>(a, b, ap, bp);
  repack_scales<<<512, 256, 0, stream>>>(sa, sb, satT, sbtT);

  dim3 grid(32 * 32);   // 1024 blocks of 128x128; 4 resident/CU
  mxfp4_gemm<<<grid, 256, 0, stream>>>((const uint8_t*)ap, (const uint8_t*)bp,
                                       satT, sbtT, out);
}

// Round 13
// 69.171 us; speedup vs baseline: 1.0088x; 1.0088x over previous
//
#include <hip/hip_runtime.h>
#include <hip/hip_bf16.h>
#include <stdint.h>

typedef __attribute__((ext_vector_type(4))) int          i32x4;
typedef __attribute__((ext_vector_type(8))) int          i32x8;
typedef __attribute__((ext_vector_type(4))) float        f32x4;
typedef __attribute__((ext_vector_type(4))) unsigned int u32x4;

#define MDIM   4096
#define NDIM   4096
#define KBYTES 2048   // K=4096 fp4 elems -> 2048 packed bytes per row
#define NKBLK  128    // K/32 scale blocks per row

#define BM   128
#define BN   128
#define BKB  128                 // K-bytes per step (= 256 fp4 elems = 8 scale blocks)
#define KT   (KBYTES / BKB)      // 16 K-steps

#define BARF()  asm volatile("s_barrier" ::: "memory")
#define LGKM0() asm volatile("s_waitcnt lgkmcnt(0)" ::: "memory")
#define VM0()   asm volatile("s_waitcnt vmcnt(0)" ::: "memory")

// ---------------- repack bytes: int32-per-byte -> packed bytes (u32x4) ----------
// grid = 524288 threads: one u32x4 (16 packed bytes) per matrix per thread.
__global__ void repack_bytes(const int* __restrict__ a, const int* __restrict__ b,
                             u32x4* __restrict__ ap, u32x4* __restrict__ bp) {
  const size_t i = (size_t)(blockIdx.x * blockDim.x + threadIdx.x);
  uint32_t r[4], s[4];
#pragma unroll
  for (int q = 0; q < 4; ++q) {
    i32x4 va = *(const i32x4*)(a + i * 16 + q * 4);
    r[q] = (uint32_t)(va.x & 255) | ((uint32_t)(va.y & 255) << 8) |
           ((uint32_t)(va.z & 255) << 16) | ((uint32_t)(va.w & 255) << 24);
    i32x4 vb = *(const i32x4*)(b + i * 16 + q * 4);
    s[q] = (uint32_t)(vb.x & 255) | ((uint32_t)(vb.y & 255) << 8) |
           ((uint32_t)(vb.z & 255) << 16) | ((uint32_t)(vb.w & 255) << 24);
  }
  u32x4 rv = {r[0], r[1], r[2], r[3]};
  u32x4 sv = {s[0], s[1], s[2], s[3]};
  ap[i] = rv;
  bp[i] = sv;
}

// ---- scale repack with LDS transpose (R12-proven, ~14us total with bytes) -----
// Target layout (R10/R11-proven): [kt(16)][rowblk(32)][kb&7(8)][m&15(16)][(m>>4)&7(8)]
// One (kt,rowblk) block = 1 KB. Grid: 512 blocks (kt = b&15, rowblk = b>>4).
__global__ void repack_scales(const float* __restrict__ sa, const float* __restrict__ sb,
                              uint8_t* __restrict__ satT, uint8_t* __restrict__ sbtT) {
  __shared__ uint8_t ls[2][1024];
  const int kt = blockIdx.x & 15, rb = blockIdx.x >> 4;
  const int t  = threadIdx.x;
  const int mm = t >> 1;                 // row within rowblk, 0..127
  const int j0 = (t & 1) * 4;            // kb sub-offset 0 or 4
  const size_t src = (size_t)(rb * 128 + mm) * 128 + kt * 8 + j0;
  const f32x4 va = *(const f32x4*)(sa + src);
  const f32x4 vb = *(const f32x4*)(sb + src);
#pragma unroll
  for (int q = 0; q < 4; ++q) {
    const int o = (j0 + q) * 128 + (mm & 15) * 8 + ((mm >> 4) & 7);
    ls[0][o] = (uint8_t)(int)va[q];
    ls[1][o] = (uint8_t)(int)vb[q];
  }
  __syncthreads();
  const size_t dst = ((size_t)kt * 32 + rb) * 1024 + t * 4;
  *(uint32_t*)(satT + dst) = *(const uint32_t*)&ls[0][t * 4];
  *(uint32_t*)(sbtT + dst) = *(const uint32_t*)&ls[1][t * 4];
}

__device__ __forceinline__ i32x8 frag8(i32x4 v) {
  i32x8 r = {v.x, v.y, v.z, v.w, 0, 0, 0, 0};
  return r;
}

// ---- MXFP4 GEMM: R11 VERBATIM (best-known codegen: 51.4us, 2673 TF) -----------
// 128x128 tile, BK=128B, single buffer, 2 barriers/step, 32 MFMA/step/wave,
// 4 blocks/CU. LDS: A 16K + B 16K + scales 2K = 34816 B.
__global__ __launch_bounds__(256, 4) void mxfp4_gemm(
    const uint8_t* __restrict__ ap, const uint8_t* __restrict__ bp,
    const uint8_t* __restrict__ satT, const uint8_t* __restrict__ sbtT,
    float* __restrict__ out) {
  __shared__ __align__(16) uint8_t lds[34816];

  const int tid  = threadIdx.x;
  const int lane = tid & 63;
  const int w    = tid >> 6;        // wave 0..3
  const int wrow = w >> 1;          // 2x2 wave grid, 64x64 out each
  const int wcol = w & 1;
  const int g    = lane >> 4;       // k-group 0..3 (one scale block each)
  const int l15  = lane & 15;
  const int lx   = lane & 7;        // read-side xor (== frag row & 7)

  // XCD-aware bijective swizzle (nwg=1024, %8==0)
  const int wgid = (blockIdx.x & 7) * 128 + (blockIdx.x >> 3);
  const int bx = wgid & 31;
  const int by = wgid >> 5;

  const uint8_t* aBase = ap + (size_t)(by * BM) * KBYTES;
  const uint8_t* bBase = bp + (size_t)(bx * BN) * KBYTES;
  uint8_t* const lA  = lds;
  uint8_t* const lB  = lds + 16384;
  uint8_t* const scb = lds + 32768;

  // R1-proven zero-conflict swizzle: LDS[row][d] holds global slot d^(row&7);
  // read slot for (kw,g) = (kw*4+g) ^ (row&7).
  const int srow  = lane >> 3;              // 0..7 within an 8-row chunk
  const int sslot = (lane & 7) ^ srow;      // involution, pre-swizzled source
  const int soff  = srow * KBYTES + sslot * 16;
  const int arow0 = w * 32;                 // each wave stages 32 A + 32 B rows

// 8 data ops (4 chunks x 1KB for A, same for B) + 2 scale ops = 10 vmem/wave/step
#define STAGE(ktX)                                                                        \
  do {                                                                                    \
    _Pragma("unroll")                                                                     \
    for (int c = 0; c < 4; ++c) {                                                         \
      const int r0 = arow0 + c * 8;                                                       \
      __builtin_amdgcn_global_load_lds(                                                   \
          (__attribute__((address_space(1))) void*)(aBase + (size_t)r0 * KBYTES + (ktX) * BKB + soff), \
          (__attribute__((address_space(3))) void*)(lA + r0 * 128), 16, 0, 0);            \
      __builtin_amdgcn_global_load_lds(                                                   \
          (__attribute__((address_space(1))) void*)(bBase + (size_t)r0 * KBYTES + (ktX) * BKB + soff), \
          (__attribute__((address_space(3))) void*)(lB + r0 * 128), 16, 0, 0);            \
    }                                                                                     \
    __builtin_amdgcn_global_load_lds(                                                     \
        (__attribute__((address_space(1))) void*)(satT + ((size_t)(ktX) * 32 + by) * 1024 + lane * 16), \
        (__attribute__((address_space(3))) void*)(scb + lane * 16), 16, 0, 0);            \
    __builtin_amdgcn_global_load_lds(                                                     \
        (__attribute__((address_space(1))) void*)(sbtT + ((size_t)(ktX) * 32 + bx) * 1024 + lane * 16), \
        (__attribute__((address_space(3))) void*)(scb + 1024 + lane * 16), 16, 0, 0);     \
  } while (0)

  f32x4 acc[4][4] = {};
  i32x4 af[4], bf[4];

  STAGE(0);

  for (int kt = 0; kt < KT; ++kt) {
    VM0();     // own 10 staging ops landed; barrier => all waves' landed
    BARF();

    // current tile's scales (one dword per operand per kw-half)
    const uint32_t sAk0 = *(const uint32_t*)(scb + (0 + g) * 128 + l15 * 8 + wrow * 4);
    const uint32_t sAk1 = *(const uint32_t*)(scb + (4 + g) * 128 + l15 * 8 + wrow * 4);
    const uint32_t sBk0 = *(const uint32_t*)(scb + 1024 + (0 + g) * 128 + l15 * 8 + wcol * 4);
    const uint32_t sBk1 = *(const uint32_t*)(scb + 1024 + (4 + g) * 128 + l15 * 8 + wcol * 4);

    // ---- kw0: K elems 0..127 of this step ----
    {
      const int slotx = ((0 + g) ^ lx) * 16;
#pragma unroll
      for (int ns = 0; ns < 4; ++ns)
        bf[ns] = *(const i32x4*)(lB + (wcol * 64 + ns * 16 + l15) * 128 + slotx);
#pragma unroll
      for (int ms = 0; ms < 4; ++ms)
        af[ms] = *(const i32x4*)(lA + (wrow * 64 + ms * 16 + l15) * 128 + slotx);
      __builtin_amdgcn_s_setprio(1);
#pragma unroll
      for (int ms = 0; ms < 4; ++ms) {
        const int sa = (int)((sAk0 >> (ms * 8)) & 0xffu);
#pragma unroll
        for (int ns = 0; ns < 4; ++ns)
          acc[ms][ns] = __builtin_amdgcn_mfma_scale_f32_16x16x128_f8f6f4(
              frag8(af[ms]), frag8(bf[ns]), acc[ms][ns], 4, 4,
              0, sa, 0, (int)((sBk0 >> (ns * 8)) & 0xffu));
      }
      __builtin_amdgcn_s_setprio(0);
    }
    // ---- kw1: K elems 128..255 (reuses af/bf regs; compiler pipelines) ----
    {
      const int slotx = ((4 + g) ^ lx) * 16;
#pragma unroll
      for (int ns = 0; ns < 4; ++ns)
        bf[ns] = *(const i32x4*)(lB + (wcol * 64 + ns * 16 + l15) * 128 + slotx);
#pragma unroll
      for (int ms = 0; ms < 4; ++ms)
        af[ms] = *(const i32x4*)(lA + (wrow * 64 + ms * 16 + l15) * 128 + slotx);
      __builtin_amdgcn_s_setprio(1);
#pragma unroll
      for (int ms = 0; ms < 4; ++ms) {
        const int sa = (int)((sAk1 >> (ms * 8)) & 0xffu);
#pragma unroll
        for (int ns = 0; ns < 4; ++ns)
          acc[ms][ns] = __builtin_amdgcn_mfma_scale_f32_16x16x128_f8f6f4(
              frag8(af[ms]), frag8(bf[ns]), acc[ms][ns], 4, 4,
              0, sa, 0, (int)((sBk1 >> (ns * 8)) & 0xffu));
      }
      __builtin_amdgcn_s_setprio(0);
    }

    LGKM0();   // all reads (frags + scale dwords) complete -> buffer free
    BARF();
    if (kt + 1 < KT) STAGE(kt + 1);   // refill single buffer for next step
  }

  // epilogue: D mapping row=(lane>>4)*4+r, col=lane&15 per 16x16 block
  float* ob = out + (size_t)(by * BM + wrow * 64) * NDIM + bx * BN + wcol * 64;
#pragma unroll
  for (int ms = 0; ms < 4; ++ms)
#pragma unroll
    for (int ns = 0; ns < 4; ++ns) {
#pragma unroll
      for (int r = 0; r < 4; ++r)
        ob[(size_t)(ms * 16 + g * 4 + r) * NDIM + ns * 16 + l15] = acc[ms][ns][r];
    }
#undef STAGE
}

extern "C" void kernel_launch(void* const* d_in, const int* in_sizes, int n_in,
                              void* d_out, int out_size, void* d_ws, size_t ws_size,
                              hipStream_t stream) {
  (void)in_sizes; (void)n_in; (void)out_size; (void)ws_size;
  const int*   a  = (const int*)d_in[0];
  const int*   b  = (const int*)d_in[1];
  const float* sa = (const float*)d_in[2];
  const float* sb = (const float*)d_in[3];
  float* out = (float*)d_out;

  uint8_t* ws = (uint8_t*)d_ws;
  u32x4*   ap   = (u32x4*)ws;                            // 8 MB packed A
  u32x4*   bp   = (u32x4*)(ws + (8u << 20));             // 8 MB packed B
  uint8_t* satT = ws + (16u << 20);                      // 512 KB scales A (tiled)
  uint8_t* sbtT = ws + (16u << 20) + (512u << 10);       // 512 KB scales B (tiled)

  repack_bytes<<<2048, 256, 0, stream>>>(a, b, ap, bp);
  repack_scales<<<512, 256, 0, stream>>>(sa, sb, satT, sbtT);

  dim3 grid(32 * 32);   // 1024 blocks of 128x128; 4 resident/CU
  mxfp4_gemm<<<grid, 256, 0, stream>>>((const uint8_t*)ap, (const uint8_t*)bp,
                                       satT, sbtT, out);
}

// Round 14
// 64.467 us; speedup vs baseline: 1.0824x; 1.0730x over previous
//
#include <hip/hip_runtime.h>
#include <hip/hip_bf16.h>
#include <stdint.h>

typedef __attribute__((ext_vector_type(4))) int          i32x4;
typedef __attribute__((ext_vector_type(8))) int          i32x8;
typedef __attribute__((ext_vector_type(4))) float        f32x4;
typedef __attribute__((ext_vector_type(4))) unsigned int u32x4;

#define MDIM   4096
#define NDIM   4096
#define KBYTES 2048   // K=4096 fp4 elems -> 2048 packed bytes per row
#define NKBLK  128    // K/32 scale blocks per row

#define BM   128
#define BN   128
#define BKB  128                 // K-bytes per step (= 256 fp4 elems = 8 scale blocks)
#define KT   (KBYTES / BKB)      // 16 K-steps

#define BARF()  asm volatile("s_barrier" ::: "memory")
#define LGKM0() asm volatile("s_waitcnt lgkmcnt(0)" ::: "memory")
#define VM0()   asm volatile("s_waitcnt vmcnt(0)" ::: "memory")

// ---- fused repack: blocks 0..2047 pack bytes; blocks 2048..2559 repack scales --
// Byte part: one u32x4 (16 packed bytes) per matrix per thread (524288 threads).
// Scale part (R12-proven LDS transpose): 512 blocks, layout
// [kt(16)][rowblk(32)][kb&7(8)][m&15(16)][(m>>4)&7(8)], 1 KB per (kt,rowblk).
__global__ void repack_all(const int* __restrict__ a, const int* __restrict__ b,
                           const float* __restrict__ sa, const float* __restrict__ sb,
                           u32x4* __restrict__ ap, u32x4* __restrict__ bp,
                           uint8_t* __restrict__ satT, uint8_t* __restrict__ sbtT) {
  __shared__ uint8_t ls[2][1024];
  if (blockIdx.x < 2048) {
    const size_t i = (size_t)(blockIdx.x * blockDim.x + threadIdx.x);
    uint32_t r[4], s[4];
#pragma unroll
    for (int q = 0; q < 4; ++q) {
      i32x4 va = *(const i32x4*)(a + i * 16 + q * 4);
      r[q] = (uint32_t)(va.x & 255) | ((uint32_t)(va.y & 255) << 8) |
             ((uint32_t)(va.z & 255) << 16) | ((uint32_t)(va.w & 255) << 24);
      i32x4 vb = *(const i32x4*)(b + i * 16 + q * 4);
      s[q] = (uint32_t)(vb.x & 255) | ((uint32_t)(vb.y & 255) << 8) |
             ((uint32_t)(vb.z & 255) << 16) | ((uint32_t)(vb.w & 255) << 24);
    }
    u32x4 rv = {r[0], r[1], r[2], r[3]};
    u32x4 sv = {s[0], s[1], s[2], s[3]};
    ap[i] = rv;
    bp[i] = sv;
  } else {
    const int blk = blockIdx.x - 2048;         // 0..511
    const int kt = blk & 15, rb = blk >> 4;
    const int t  = threadIdx.x;
    const int mm = t >> 1;                     // row within rowblk, 0..127
    const int j0 = (t & 1) * 4;                // kb sub-offset 0 or 4
    const size_t src = (size_t)(rb * 128 + mm) * 128 + kt * 8 + j0;
    const f32x4 va = *(const f32x4*)(sa + src);
    const f32x4 vb = *(const f32x4*)(sb + src);
#pragma unroll
    for (int q = 0; q < 4; ++q) {
      const int o = (j0 + q) * 128 + (mm & 15) * 8 + ((mm >> 4) & 7);
      ls[0][o] = (uint8_t)(int)va[q];
      ls[1][o] = (uint8_t)(int)vb[q];
    }
    __syncthreads();
    const size_t dst = ((size_t)kt * 32 + rb) * 1024 + t * 4;
    *(uint32_t*)(satT + dst) = *(const uint32_t*)&ls[0][t * 4];
    *(uint32_t*)(sbtT + dst) = *(const uint32_t*)&ls[1][t * 4];
  }
}

__device__ __forceinline__ i32x8 frag8(i32x4 v) {
  i32x8 r = {v.x, v.y, v.z, v.w, 0, 0, 0, 0};
  return r;
}

// ---- MXFP4 GEMM: R11/R13 K-loop VERBATIM (best-known codegen: 51.4us) ---------
// Only change: rectangular XCD mapping (8 by x 16 bx per XCD -> 6MB working set
// fits closer to the 4MB L2 than the old 4x32 = 9MB strip).
__global__ __launch_bounds__(256, 4) void mxfp4_gemm(
    const uint8_t* __restrict__ ap, const uint8_t* __restrict__ bp,
    const uint8_t* __restrict__ satT, const uint8_t* __restrict__ sbtT,
    float* __restrict__ out) {
  __shared__ __align__(16) uint8_t lds[34816];

  const int tid  = threadIdx.x;
  const int lane = tid & 63;
  const int w    = tid >> 6;        // wave 0..3
  const int wrow = w >> 1;          // 2x2 wave grid, 64x64 out each
  const int wcol = w & 1;
  const int g    = lane >> 4;       // k-group 0..3 (one scale block each)
  const int l15  = lane & 15;
  const int lx   = lane & 7;        // read-side xor (== frag row & 7)

  // Rectangular XCD mapping: XCD c = blockIdx&7 owns rect bx in [ (c&1)*16, +16 ),
  // by in [ (c>>1)*8, +8 ); within-chunk index walks bx fast (A-panel reuse).
  const int c = blockIdx.x & 7;
  const int i = blockIdx.x >> 3;    // 0..127
  const int bx = (c & 1) * 16 + (i & 15);
  const int by = (c >> 1) * 8 + (i >> 4);

  const uint8_t* aBase = ap + (size_t)(by * BM) * KBYTES;
  const uint8_t* bBase = bp + (size_t)(bx * BN) * KBYTES;
  uint8_t* const lA  = lds;
  uint8_t* const lB  = lds + 16384;
  uint8_t* const scb = lds + 32768;

  // R1-proven zero-conflict swizzle: LDS[row][d] holds global slot d^(row&7);
  // read slot for (kw,g) = (kw*4+g) ^ (row&7).
  const int srow  = lane >> 3;              // 0..7 within an 8-row chunk
  const int sslot = (lane & 7) ^ srow;      // involution, pre-swizzled source
  const int soff  = srow * KBYTES + sslot * 16;
  const int arow0 = w * 32;                 // each wave stages 32 A + 32 B rows

// 8 data ops (4 chunks x 1KB for A, same for B) + 2 scale ops = 10 vmem/wave/step
#define STAGE(ktX)                                                                        \
  do {                                                                                    \
    _Pragma("unroll")                                                                     \
    for (int cc = 0; cc < 4; ++cc) {                                                      \
      const int r0 = arow0 + cc * 8;                                                      \
      __builtin_amdgcn_global_load_lds(                                                   \
          (__attribute__((address_space(1))) void*)(aBase + (size_t)r0 * KBYTES + (ktX) * BKB + soff), \
          (__attribute__((address_space(3))) void*)(lA + r0 * 128), 16, 0, 0);            \
      __builtin_amdgcn_global_load_lds(                                                   \
          (__attribute__((address_space(1))) void*)(bBase + (size_t)r0 * KBYTES + (ktX) * BKB + soff), \
          (__attribute__((address_space(3))) void*)(lB + r0 * 128), 16, 0, 0);            \
    }                                                                                     \
    __builtin_amdgcn_global_load_lds(                                                     \
        (__attribute__((address_space(1))) void*)(satT + ((size_t)(ktX) * 32 + by) * 1024 + lane * 16), \
        (__attribute__((address_space(3))) void*)(scb + lane * 16), 16, 0, 0);            \
    __builtin_amdgcn_global_load_lds(                                                     \
        (__attribute__((address_space(1))) void*)(sbtT + ((size_t)(ktX) * 32 + bx) * 1024 + lane * 16), \
        (__attribute__((address_space(3))) void*)(scb + 1024 + lane * 16), 16, 0, 0);     \
  } while (0)

  f32x4 acc[4][4] = {};
  i32x4 af[4], bf[4];

  STAGE(0);

  for (int kt = 0; kt < KT; ++kt) {
    VM0();     // own 10 staging ops landed; barrier => all waves' landed
    BARF();

    // current tile's scales (one dword per operand per kw-half)
    const uint32_t sAk0 = *(const uint32_t*)(scb + (0 + g) * 128 + l15 * 8 + wrow * 4);
    const uint32_t sAk1 = *(const uint32_t*)(scb + (4 + g) * 128 + l15 * 8 + wrow * 4);
    const uint32_t sBk0 = *(const uint32_t*)(scb + 1024 + (0 + g) * 128 + l15 * 8 + wcol * 4);
    const uint32_t sBk1 = *(const uint32_t*)(scb + 1024 + (4 + g) * 128 + l15 * 8 + wcol * 4);

    // ---- kw0: K elems 0..127 of this step ----
    {
      const int slotx = ((0 + g) ^ lx) * 16;
#pragma unroll
      for (int ns = 0; ns < 4; ++ns)
        bf[ns] = *(const i32x4*)(lB + (wcol * 64 + ns * 16 + l15) * 128 + slotx);
#pragma unroll
      for (int ms = 0; ms < 4; ++ms)
        af[ms] = *(const i32x4*)(lA + (wrow * 64 + ms * 16 + l15) * 128 + slotx);
      __builtin_amdgcn_s_setprio(1);
#pragma unroll
      for (int ms = 0; ms < 4; ++ms) {
        const int sa = (int)((sAk0 >> (ms * 8)) & 0xffu);
#pragma unroll
        for (int ns = 0; ns < 4; ++ns)
          acc[ms][ns] = __builtin_amdgcn_mfma_scale_f32_16x16x128_f8f6f4(
              frag8(af[ms]), frag8(bf[ns]), acc[ms][ns], 4, 4,
              0, sa, 0, (int)((sBk0 >> (ns * 8)) & 0xffu));
      }
      __builtin_amdgcn_s_setprio(0);
    }
    // ---- kw1: K elems 128..255 (reuses af/bf regs; compiler pipelines) ----
    {
      const int slotx = ((4 + g) ^ lx) * 16;
#pragma unroll
      for (int ns = 0; ns < 4; ++ns)
        bf[ns] = *(const i32x4*)(lB + (wcol * 64 + ns * 16 + l15) * 128 + slotx);
#pragma unroll
      for (int ms = 0; ms < 4; ++ms)
        af[ms] = *(const i32x4*)(lA + (wrow * 64 + ms * 16 + l15) * 128 + slotx);
      __builtin_amdgcn_s_setprio(1);
#pragma unroll
      for (int ms = 0; ms < 4; ++ms) {
        const int sa = (int)((sAk1 >> (ms * 8)) & 0xffu);
#pragma unroll
        for (int ns = 0; ns < 4; ++ns)
          acc[ms][ns] = __builtin_amdgcn_mfma_scale_f32_16x16x128_f8f6f4(
              frag8(af[ms]), frag8(bf[ns]), acc[ms][ns], 4, 4,
              0, sa, 0, (int)((sBk1 >> (ns * 8)) & 0xffu));
      }
      __builtin_amdgcn_s_setprio(0);
    }

    LGKM0();   // all reads (frags + scale dwords) complete -> buffer free
    BARF();
    if (kt + 1 < KT) STAGE(kt + 1);   // refill single buffer for next step
  }

  // epilogue: D mapping row=(lane>>4)*4+r, col=lane&15 per 16x16 block
  float* ob = out + (size_t)(by * BM + wrow * 64) * NDIM + bx * BN + wcol * 64;
#pragma unroll
  for (int ms = 0; ms < 4; ++ms)
#pragma unroll
    for (int ns = 0; ns < 4; ++ns) {
#pragma unroll
      for (int r = 0; r < 4; ++r)
        ob[(size_t)(ms * 16 + g * 4 + r) * NDIM + ns * 16 + l15] = acc[ms][ns][r];
    }
#undef STAGE
}

extern "C" void kernel_launch(void* const* d_in, const int* in_sizes, int n_in,
                              void* d_out, int out_size, void* d_ws, size_t ws_size,
                              hipStream_t stream) {
  (void)in_sizes; (void)n_in; (void)out_size; (void)ws_size;
  const int*   a  = (const int*)d_in[0];
  const int*   b  = (const int*)d_in[1];
  const float* sa = (const float*)d_in[2];
  const float* sb = (const float*)d_in[3];
  float* out = (float*)d_out;

  uint8_t* ws = (uint8_t*)d_ws;
  u32x4*   ap   = (u32x4*)ws;                            // 8 MB packed A
  u32x4*   bp   = (u32x4*)(ws + (8u << 20));             // 8 MB packed B
  uint8_t* satT = ws + (16u << 20);                      // 512 KB scales A (tiled)
  uint8_t* sbtT = ws + (16u << 20) + (512u << 10);       // 512 KB scales B (tiled)

  repack_all<<<2560, 256, 0, stream>>>(a, b, sa, sb, ap, bp, satT, sbtT);

  dim3 grid(32 * 32);   // 1024 blocks of 128x128; 4 resident/CU
  mxfp4_gemm<<<grid, 256, 0, stream>>>((const uint8_t*)ap, (const uint8_t*)bp,
                                       satT, sbtT, out);
}